// Round 4
// baseline (262.803 us; speedup 1.0000x reference)
//
#include <hip/hip_runtime.h>
#include <hip/hip_bf16.h>

typedef _Float16 half8_t __attribute__((ext_vector_type(8)));
typedef _Float16 half4_t __attribute__((ext_vector_type(4)));
typedef float    f32x4   __attribute__((ext_vector_type(4)));
typedef float    f32x16  __attribute__((ext_vector_type(16)));

#define CDIM 512
#define NHEAD 8
#define HD 64
#define NTOK 512
#define NWIN 64
#define TC 1536  // 3*C

// ws panel layout: per (local window w): 24 panels of 32768 halfs (65536 B)
//   panel (w*24 + 0*8 + h): Q  [n][d]   (later overwritten by attention output [n][d])
//   panel (w*24 + 1*8 + h): K  [n][d]
//   panel (w*24 + 2*8 + h): V key-permuted: [kg(32)][hh(2)][d(64)][e(8)]
//     key n -> kg=n>>4, hh=(n>>2)&1, e=(n&3)+4*((n>>3)&1)

// ---------------- prep: fp32 -> fp16 transposes via LDS tiles ----------------
__global__ __launch_bounds__(256) void prep_weights(
    const float* __restrict__ wqkv, const float* __restrict__ wproj,
    _Float16* __restrict__ wqkvT, _Float16* __restrict__ wprojT) {
  __shared__ _Float16 T[64 * 65];
  int b = blockIdx.x;
  const float* src; _Float16* dst; int Cc, r0, c0;
  if (b < 192) {  // wqkv [512][1536] -> wqkvT [1536][512]
    src = wqkv; dst = wqkvT; Cc = 1536;
    c0 = (b % 24) * 64; r0 = (b / 24) * 64;
  } else {        // wproj [512][512] -> wprojT [512][512]
    b -= 192; src = wproj; dst = wprojT; Cc = 512;
    c0 = (b & 7) * 64; r0 = (b >> 3) * 64;
  }
  const int t = threadIdx.x;
#pragma unroll
  for (int i = 0; i < 16; ++i) {  // coalesced read 64x64 fp32, store [r][c] padded
    int idx = i * 256 + t, rr = idx >> 6, cc = idx & 63;
    T[rr * 65 + cc] = (_Float16)src[(size_t)(r0 + rr) * Cc + c0 + cc];
  }
  __syncthreads();
#pragma unroll
  for (int i = 0; i < 2; ++i) {  // transposed read, coalesced 16B writes
    int idx = i * 256 + t, ol = idx >> 3, c8 = idx & 7;
    half8_t vv;
#pragma unroll
    for (int e = 0; e < 8; ++e) vv[e] = T[(c8 * 8 + e) * 65 + ol];
    *(half8_t*)(dst + (size_t)(c0 + ol) * 512 + r0 + c8 * 8) = vv;
  }
}

// ---------------- GEMM1 v2: BK=64, swizzled LDS, reg-staged prefetch ----------------
__global__ __launch_bounds__(256) void gemm1_qkv(
    const float* __restrict__ x,       // chunk base: [nw*512][512] fp32
    const _Float16* __restrict__ wT,   // [1536][512] fp16
    const float* __restrict__ bias,    // [1536]
    _Float16* __restrict__ qkv) {
  __shared__ __align__(16) _Float16 smem[2 * 128 * 64];  // As 16KB | Bs 16KB; epilogue C 32KB
  char* AsB = (char*)smem;
  char* BsB = AsB + 16384;
  const int tid = threadIdx.x;
  const int l = tid & 63;
  const int wid = tid >> 6;
  const int wr = wid >> 1, wc = wid & 1;
  const int lr = l & 15, g = l >> 4;
  const int swzf = (lr & 7) << 4;  // frag-read swizzle (row&7 == lr&7 for 16-aligned tiles)
  const int m0 = blockIdx.x * 128;
  const int cb = blockIdx.y * 128;  // channel base 0..1408
  const int j = cb >> 9;            // 0=Q 1=K 2=V

  float4 av[8];
  half8_t bv[4];
#pragma unroll
  for (int i = 0; i < 8; ++i) {  // prologue loads ks=0
    int idx = i * 256 + tid, row = idx >> 4, c4 = idx & 15;
    av[i] = *(const float4*)(x + (size_t)(m0 + row) * CDIM + c4 * 4);
  }
#pragma unroll
  for (int i = 0; i < 4; ++i) {
    int idx = i * 256 + tid, row = idx >> 3, c = idx & 7;
    bv[i] = *(const half8_t*)(wT + (size_t)(cb + row) * CDIM + c * 8);
  }

  f32x4 acc[4][4] = {};
  for (int ks = 0; ks < 8; ++ks) {
    __syncthreads();  // previous compute done reading LDS
#pragma unroll
    for (int i = 0; i < 8; ++i) {  // A: fp32->fp16, swizzled 8B writes
      int idx = i * 256 + tid, row = idx >> 4, c4 = idx & 15;
      half4_t hv = {(_Float16)av[i].x, (_Float16)av[i].y, (_Float16)av[i].z, (_Float16)av[i].w};
      *(half4_t*)(AsB + row * 128 + ((c4 * 8) ^ ((row & 7) << 4))) = hv;
    }
#pragma unroll
    for (int i = 0; i < 4; ++i) {  // B: swizzled 16B writes
      int idx = i * 256 + tid, row = idx >> 3, c = idx & 7;
      *(half8_t*)(BsB + row * 128 + ((c * 16) ^ ((row & 7) << 4))) = bv[i];
    }
    __syncthreads();
    if (ks < 7) {  // prefetch next K-tile; lands under the 32 MFMAs below
      const int k0 = (ks + 1) * 64;
#pragma unroll
      for (int i = 0; i < 8; ++i) {
        int idx = i * 256 + tid, row = idx >> 4, c4 = idx & 15;
        av[i] = *(const float4*)(x + (size_t)(m0 + row) * CDIM + k0 + c4 * 4);
      }
#pragma unroll
      for (int i = 0; i < 4; ++i) {
        int idx = i * 256 + tid, row = idx >> 3, c = idx & 7;
        bv[i] = *(const half8_t*)(wT + (size_t)(cb + row) * CDIM + k0 + c * 8);
      }
    }
#pragma unroll
    for (int kk = 0; kk < 2; ++kk) {
      half8_t a[4], b[4];
#pragma unroll
      for (int mt = 0; mt < 4; ++mt) {
        int row = wr * 64 + mt * 16 + lr;
        a[mt] = *(const half8_t*)(AsB + row * 128 + ((kk * 64 + g * 16) ^ swzf));
      }
#pragma unroll
      for (int nt = 0; nt < 4; ++nt) {
        int row = wc * 64 + nt * 16 + lr;
        b[nt] = *(const half8_t*)(BsB + row * 128 + ((kk * 64 + g * 16) ^ swzf));
      }
#pragma unroll
      for (int mt = 0; mt < 4; ++mt)
#pragma unroll
        for (int nt = 0; nt < 4; ++nt)
          acc[mt][nt] = __builtin_amdgcn_mfma_f32_16x16x32_f16(a[mt], b[nt], acc[mt][nt], 0, 0, 0);
    }
  }
  __syncthreads();  // LDS free for epilogue reuse

  if (j == 2) {  // V: key-permuted panels, 8B stores (proven path)
#pragma unroll
    for (int nt = 0; nt < 4; ++nt) {
      const int ch = cb + wc * 64 + nt * 16 + lr;
      const int h = (ch >> 6) & 7, d = ch & 63;
      const float bvs = bias[ch];
#pragma unroll
      for (int mt = 0; mt < 4; ++mt) {
        const int row = m0 + wr * 64 + mt * 16 + g * 4;
        const int wL = row >> 9, n = row & 511;
        _Float16* panel = qkv + ((size_t)(wL * 24 + 16 + h) << 15);
        const int kg = n >> 4, hh = (n >> 2) & 1, e4 = (n & 8) >> 1;
        half4_t pk = {(_Float16)(acc[mt][nt][0] + bvs), (_Float16)(acc[mt][nt][1] + bvs),
                      (_Float16)(acc[mt][nt][2] + bvs), (_Float16)(acc[mt][nt][3] + bvs)};
        *(half4_t*)(panel + ((size_t)(kg * 2 + hh) * 64 + d) * 8 + e4) = pk;
      }
    }
  } else {  // Q/K: acc -> swizzled LDS C-tile -> coalesced 16B stores
    char* CB = AsB;
#pragma unroll
    for (int nt = 0; nt < 4; ++nt) {
      const int chl = wc * 64 + nt * 16 + lr;
      const float bvs = bias[cb + chl];
#pragma unroll
      for (int mt = 0; mt < 4; ++mt) {
#pragma unroll
        for (int r = 0; r < 4; ++r) {
          int nl = wr * 64 + mt * 16 + g * 4 + r;
          *(_Float16*)(CB + nl * 256 + ((chl * 2) ^ ((nl & 7) << 5))) =
              (_Float16)(acc[mt][nt][r] + bvs);
        }
      }
    }
    __syncthreads();
#pragma unroll
    for (int i = 0; i < 8; ++i) {
      int idx = i * 256 + tid, nl = idx >> 4, c8 = idx & 15;
      half8_t vv = *(const half8_t*)(CB + nl * 256 + ((c8 * 16) ^ ((nl & 7) << 5)));
      int chg = cb + c8 * 8;
      int h = (chg >> 6) & 7, d = chg & 63;
      int ng = m0 + nl, wL = ng >> 9, nn = ng & 511;
      _Float16* panel = qkv + ((size_t)(wL * 24 + j * 8 + h) << 15);
      *(half8_t*)(panel + (size_t)nn * 64 + d) = vv;
    }
  }
}

// ---------------- attention: swapped QK^T, lane-local softmax, zero LDS ----------------
__global__ __launch_bounds__(256) void attn_win(_Float16* __restrict__ qkv) {
  const int tid = threadIdx.x;
  const int l = tid & 63;
  const int wid = tid >> 6;
  const int q32 = l & 31;
  const int h2 = l >> 5;
  const int b = blockIdx.x;
  const int qc = b & 3;
  const int h = (b >> 2) & 7;
  const int w = b >> 5;
  _Float16* Qp = qkv + ((size_t)(w * 24 + h) << 15);
  const _Float16* Kp = qkv + ((size_t)(w * 24 + 8 + h) << 15);
  const _Float16* Vp = qkv + ((size_t)(w * 24 + 16 + h) << 15);
  const int qrow = qc * 128 + wid * 32 + q32;

  half8_t qf[4];
#pragma unroll
  for (int j = 0; j < 4; ++j)
    qf[j] = *(const half8_t*)(Qp + (size_t)qrow * 64 + j * 16 + h2 * 8);

  f32x16 o0 = {}, o1 = {};
  float m_run = -1e30f, lsum = 0.f;

  for (int kt = 0; kt < 16; ++kt) {
    half8_t kf[4];
#pragma unroll
    for (int j = 0; j < 4; ++j)
      kf[j] = *(const half8_t*)(Kp + (size_t)(kt * 32 + q32) * 64 + j * 16 + h2 * 8);
    f32x16 s = {};
#pragma unroll
    for (int j = 0; j < 4; ++j)
      s = __builtin_amdgcn_mfma_f32_32x32x16_f16(kf[j], qf[j], s, 0, 0, 0);

    float tmax = s[0];
#pragma unroll
    for (int r = 1; r < 16; ++r) tmax = fmaxf(tmax, s[r]);
    tmax = fmaxf(tmax, __shfl_xor(tmax, 32));
    if (!__all(tmax <= m_run + 8.f)) {  // T13 defer-max
      float mNew = fmaxf(m_run, tmax);
      float sc = __expf(m_run - mNew);
      lsum *= sc;
#pragma unroll
      for (int r = 0; r < 16; ++r) { o0[r] *= sc; o1[r] *= sc; }
      m_run = mNew;
    }
    float p[16], tsum = 0.f;
#pragma unroll
    for (int r = 0; r < 16; ++r) { p[r] = __expf(s[r] - m_run); tsum += p[r]; }
    tsum += __shfl_xor(tsum, 32);
    lsum += tsum;

    half8_t pf0, pf1;
#pragma unroll
    for (int e = 0; e < 8; ++e) { pf0[e] = (_Float16)p[e]; pf1[e] = (_Float16)(p[8 + e]); }

    const _Float16* vb = Vp + (size_t)(kt * 4 + h2) * 512 + q32 * 8;
    half8_t vf;
    vf = *(const half8_t*)(vb);
    o0 = __builtin_amdgcn_mfma_f32_32x32x16_f16(vf, pf0, o0, 0, 0, 0);
    vf = *(const half8_t*)(vb + 256);
    o1 = __builtin_amdgcn_mfma_f32_32x32x16_f16(vf, pf0, o1, 0, 0, 0);
    vf = *(const half8_t*)(vb + 1024);
    o0 = __builtin_amdgcn_mfma_f32_32x32x16_f16(vf, pf1, o0, 0, 0, 0);
    vf = *(const half8_t*)(vb + 1280);
    o1 = __builtin_amdgcn_mfma_f32_32x32x16_f16(vf, pf1, o1, 0, 0, 0);
  }
  const float inv = 1.0f / lsum;
#pragma unroll
  for (int rq = 0; rq < 4; ++rq) {
    half4_t v0, v1;
#pragma unroll
    for (int i = 0; i < 4; ++i) {
      v0[i] = (_Float16)(o0[rq * 4 + i] * inv);
      v1[i] = (_Float16)(o1[rq * 4 + i] * inv);
    }
    *(half4_t*)(Qp + (size_t)qrow * 64 + 8 * rq + 4 * h2) = v0;
    *(half4_t*)(Qp + (size_t)qrow * 64 + 32 + 8 * rq + 4 * h2) = v1;
  }
}

// ---------------- GEMM2: out = attn_out @ Wproj + b ----------------
__global__ __launch_bounds__(256) void gemm2_proj(
    const _Float16* __restrict__ qkv,
    const _Float16* __restrict__ wpT,  // [512][512]
    const float* __restrict__ bias,    // [512]
    float* __restrict__ out) {
  const int tid = threadIdx.x, l = tid & 63;
  const int wid = tid >> 6, wr = wid >> 1, wc = wid & 1;
  const int lr = l & 15, lk8 = (l >> 4) * 8;
  const int m0 = blockIdx.x * 128, n0 = blockIdx.y * 128;
  size_t aBase[4];
#pragma unroll
  for (int mt = 0; mt < 4; ++mt) {
    int row = m0 + wr * 64 + mt * 16 + lr;
    int wL = row >> 9, n = row & 511;
    aBase[mt] = ((size_t)(wL * 24) << 15) + (size_t)n * 64 + lk8;
  }
  size_t bBase[4];
#pragma unroll
  for (int nt = 0; nt < 4; ++nt)
    bBase[nt] = (size_t)(n0 + wc * 64 + nt * 16 + lr) * 512 + lk8;

  f32x4 acc[4][4] = {};
  for (int ks = 0; ks < 16; ++ks) {
    half8_t a[4], b[4];
    size_t aoff = (size_t)(ks >> 1) * 32768 + (size_t)(ks & 1) * 32;
#pragma unroll
    for (int mt = 0; mt < 4; ++mt) a[mt] = *(const half8_t*)(qkv + aBase[mt] + aoff);
#pragma unroll
    for (int nt = 0; nt < 4; ++nt) b[nt] = *(const half8_t*)(wpT + bBase[nt] + ks * 32);
#pragma unroll
    for (int mt = 0; mt < 4; ++mt)
#pragma unroll
      for (int nt = 0; nt < 4; ++nt)
        acc[mt][nt] = __builtin_amdgcn_mfma_f32_16x16x32_f16(a[mt], b[nt], acc[mt][nt], 0, 0, 0);
  }
#pragma unroll
  for (int nt = 0; nt < 4; ++nt) {
    int col = n0 + wc * 64 + nt * 16 + lr;
    float bv = bias[col];
#pragma unroll
    for (int mt = 0; mt < 4; ++mt) {
      int row = m0 + wr * 64 + mt * 16 + ((l >> 4) << 2);
#pragma unroll
      for (int r = 0; r < 4; ++r)
        out[(size_t)(row + r) * 512 + col] = acc[mt][nt][r] + bv;
    }
  }
}

extern "C" void kernel_launch(void* const* d_in, const int* in_sizes, int n_in,
                              void* d_out, int out_size, void* d_ws, size_t ws_size,
                              hipStream_t stream) {
  const float* x = (const float*)d_in[0];
  const float* wqkv = (const float*)d_in[1];
  const float* bqkv = (const float*)d_in[2];
  const float* wproj = (const float*)d_in[3];
  const float* bproj = (const float*)d_in[4];
  float* out = (float*)d_out;

  _Float16* wqkvT = (_Float16*)d_ws;
  _Float16* wprojT = wqkvT + (size_t)TC * CDIM;
  _Float16* qkvws = wprojT + (size_t)CDIM * CDIM;
  const size_t fixed = ((size_t)TC * CDIM + (size_t)CDIM * CDIM) * sizeof(_Float16);
  const size_t perwin = (size_t)24 * 32768 * sizeof(_Float16);
  int nw = 64;
  while (nw > 1 && fixed + (size_t)nw * perwin > ws_size) nw >>= 1;

  prep_weights<<<dim3(256), 256, 0, stream>>>(wqkv, wproj, wqkvT, wprojT);
  for (int wbase = 0; wbase < NWIN; wbase += nw) {
    const float* xc = x + (size_t)wbase * NTOK * CDIM;
    float* oc = out + (size_t)wbase * NTOK * CDIM;
    gemm1_qkv<<<dim3(nw * 4, 12), 256, 0, stream>>>(xc, wqkvT, bqkv, qkvws);
    attn_win<<<dim3(nw * 32), 256, 0, stream>>>(qkvws);
    gemm2_proj<<<dim3(nw * 4, 4), 256, 0, stream>>>(qkvws, wprojT, bproj, oc);
  }
}

// Round 5
// 260.435 us; speedup vs baseline: 1.0091x; 1.0091x over previous
//
#include <hip/hip_runtime.h>
#include <hip/hip_bf16.h>

typedef _Float16 half8_t __attribute__((ext_vector_type(8)));
typedef _Float16 half4_t __attribute__((ext_vector_type(4)));
typedef float    f32x4   __attribute__((ext_vector_type(4)));
typedef float    f32x16  __attribute__((ext_vector_type(16)));

#define CDIM 512
#define NHEAD 8
#define HD 64
#define NTOK 512
#define NWIN 64
#define TC 1536  // 3*C

// global->LDS direct DMA, 16B per lane, wave-uniform LDS base (m97 pattern)
#define GLL16(g, l)                                                        \
  __builtin_amdgcn_global_load_lds((const __attribute__((address_space(1))) void*)(g), \
                                   (__attribute__((address_space(3))) void*)(l), 16, 0, 0)

// ws panel layout: per (local window w): 24 panels of 32768 halfs (65536 B)
//   panel (w*24 + 0*8 + h): Q  [n][d]   (later overwritten by attention output [n][d])
//   panel (w*24 + 1*8 + h): K  [n][d]
//   panel (w*24 + 2*8 + h): V key-permuted: [kg(32)][hh(2)][d(64)][e(8)]
//     key n -> kg=n>>4, hh=(n>>2)&1, e=(n&3)+4*((n>>3)&1)

// ---------------- x fp32 -> fp16 (one pass; removes per-use cvt in gemm1) ----------------
__global__ __launch_bounds__(256) void cvt_x(const float* __restrict__ x,
                                             _Float16* __restrict__ x16, int n8) {
  int i = blockIdx.x * 256 + threadIdx.x;
  if (i < n8) {
    float4 v0 = *(const float4*)(x + (size_t)i * 8);
    float4 v1 = *(const float4*)(x + (size_t)i * 8 + 4);
    half8_t h = {(_Float16)v0.x, (_Float16)v0.y, (_Float16)v0.z, (_Float16)v0.w,
                 (_Float16)v1.x, (_Float16)v1.y, (_Float16)v1.z, (_Float16)v1.w};
    *(half8_t*)(x16 + (size_t)i * 8) = h;
  }
}

// ---------------- prep: fp32 -> fp16 transposes via LDS tiles ----------------
__global__ __launch_bounds__(256) void prep_weights(
    const float* __restrict__ wqkv, const float* __restrict__ wproj,
    _Float16* __restrict__ wqkvT, _Float16* __restrict__ wprojT) {
  __shared__ _Float16 T[64 * 65];
  int b = blockIdx.x;
  const float* src; _Float16* dst; int Cc, r0, c0;
  if (b < 192) {  // wqkv [512][1536] -> wqkvT [1536][512]
    src = wqkv; dst = wqkvT; Cc = 1536;
    c0 = (b % 24) * 64; r0 = (b / 24) * 64;
  } else {        // wproj [512][512] -> wprojT [512][512]
    b -= 192; src = wproj; dst = wprojT; Cc = 512;
    c0 = (b & 7) * 64; r0 = (b >> 3) * 64;
  }
  const int t = threadIdx.x;
#pragma unroll
  for (int i = 0; i < 16; ++i) {
    int idx = i * 256 + t, rr = idx >> 6, cc = idx & 63;
    T[rr * 65 + cc] = (_Float16)src[(size_t)(r0 + rr) * Cc + c0 + cc];
  }
  __syncthreads();
#pragma unroll
  for (int i = 0; i < 2; ++i) {
    int idx = i * 256 + t, ol = idx >> 3, c8 = idx & 7;
    half8_t vv;
#pragma unroll
    for (int e = 0; e < 8; ++e) vv[e] = T[(c8 * 8 + e) * 65 + ol];
    *(half8_t*)(dst + (size_t)(c0 + ol) * 512 + r0 + c8 * 8) = vv;
  }
}

// ---------------- GEMM1 v3: global_load_lds both operands, dbuf, 1 barrier/K-step ----------------
// A = x16 [nw*512][512], B = wT [1536][512], both staged as [128][64] fp16 tiles with
// pre-swizzled SOURCE + swizzled frag-read (involution col16 ^= (row&7)<<4; rule #21).
__global__ __launch_bounds__(256) void gemm1_qkv(
    const _Float16* __restrict__ x16,
    const _Float16* __restrict__ wT,
    const float* __restrict__ bias,
    _Float16* __restrict__ qkv) {
  __shared__ __align__(16) _Float16 smem[4 * 128 * 64];  // As[2] 32KB | Bs[2] 32KB
  char* base = (char*)smem;
  const int tid = threadIdx.x;
  const int l = tid & 63;
  const int wid = tid >> 6;
  const int wr = wid >> 1, wc = wid & 1;
  const int lr = l & 15, g = l >> 4;
  const int swzf = (lr & 7) << 4;
  const int m0 = blockIdx.x * 128;
  const int cb = blockIdx.y * 128;  // channel base 0..1408
  const int j = cb >> 9;            // 0=Q 1=K 2=V

  // per-thread gll source geometry: chunk = wid*4+i covers rows chunk*8..+8
  const int srow = l >> 3;                       // row within 8-row chunk
  const int scol = 16 * ((l & 7) ^ srow);        // pre-swizzled source col byte
  const size_t aRowB = (size_t)(m0 + srow) * 1024 + scol;  // + chunk*8*1024 + k0*2
  const size_t bRowB = (size_t)(cb + srow) * 1024 + scol;

#define STAGE_G1(buf, k0)                                                         \
  {                                                                               \
    char* Ad = base + (buf)*16384 + wid * 4096;                                   \
    char* Bd = base + 32768 + (buf)*16384 + wid * 4096;                           \
    _Pragma("unroll") for (int i = 0; i < 4; ++i) {                               \
      int chunk = wid * 4 + i;                                                    \
      GLL16((const char*)x16 + aRowB + (size_t)chunk * 8192 + (k0)*2, Ad + i * 1024); \
      GLL16((const char*)wT + bRowB + (size_t)chunk * 8192 + (k0)*2, Bd + i * 1024);  \
    }                                                                             \
  }

  STAGE_G1(0, 0);
  __syncthreads();  // drains vmcnt for all waves

  f32x4 acc[4][4] = {};
  for (int ks = 0; ks < 8; ++ks) {
    const int cur = ks & 1;
    if (ks < 7) STAGE_G1(cur ^ 1, (ks + 1) * 64);  // flies under the MFMAs below
    char* AsB = base + cur * 16384;
    char* BsB = base + 32768 + cur * 16384;
#pragma unroll
    for (int kk = 0; kk < 2; ++kk) {
      half8_t a[4], b[4];
#pragma unroll
      for (int mt = 0; mt < 4; ++mt) {
        int row = wr * 64 + mt * 16 + lr;
        a[mt] = *(const half8_t*)(AsB + row * 128 + ((kk * 64 + g * 16) ^ swzf));
      }
#pragma unroll
      for (int nt = 0; nt < 4; ++nt) {
        int row = wc * 64 + nt * 16 + lr;
        b[nt] = *(const half8_t*)(BsB + row * 128 + ((kk * 64 + g * 16) ^ swzf));
      }
#pragma unroll
      for (int mt = 0; mt < 4; ++mt)
#pragma unroll
        for (int nt = 0; nt < 4; ++nt)
          acc[mt][nt] = __builtin_amdgcn_mfma_f32_16x16x32_f16(a[mt], b[nt], acc[mt][nt], 0, 0, 0);
    }
    __syncthreads();  // waves done reading cur; gll into cur^1 drained for next iter
  }

  if (j == 2) {  // V: key-permuted panels, 8B stores
#pragma unroll
    for (int nt = 0; nt < 4; ++nt) {
      const int ch = cb + wc * 64 + nt * 16 + lr;
      const int h = (ch >> 6) & 7, d = ch & 63;
      const float bvs = bias[ch];
#pragma unroll
      for (int mt = 0; mt < 4; ++mt) {
        const int row = m0 + wr * 64 + mt * 16 + g * 4;
        const int wL = row >> 9, n = row & 511;
        _Float16* panel = qkv + ((size_t)(wL * 24 + 16 + h) << 15);
        const int kg = n >> 4, hh = (n >> 2) & 1, e4 = (n & 8) >> 1;
        half4_t pk = {(_Float16)(acc[mt][nt][0] + bvs), (_Float16)(acc[mt][nt][1] + bvs),
                      (_Float16)(acc[mt][nt][2] + bvs), (_Float16)(acc[mt][nt][3] + bvs)};
        *(half4_t*)(panel + ((size_t)(kg * 2 + hh) * 64 + d) * 8 + e4) = pk;
      }
    }
  } else {  // Q/K: acc -> swizzled LDS C-tile -> coalesced 16B stores
    char* CB = base;
#pragma unroll
    for (int nt = 0; nt < 4; ++nt) {
      const int chl = wc * 64 + nt * 16 + lr;
      const float bvs = bias[cb + chl];
#pragma unroll
      for (int mt = 0; mt < 4; ++mt) {
#pragma unroll
        for (int r = 0; r < 4; ++r) {
          int nl = wr * 64 + mt * 16 + g * 4 + r;
          *(_Float16*)(CB + nl * 256 + ((chl * 2) ^ ((nl & 7) << 5))) =
              (_Float16)(acc[mt][nt][r] + bvs);
        }
      }
    }
    __syncthreads();
#pragma unroll
    for (int i = 0; i < 8; ++i) {
      int idx = i * 256 + tid, nl = idx >> 4, c8 = idx & 15;
      half8_t vv = *(const half8_t*)(CB + nl * 256 + ((c8 * 16) ^ ((nl & 7) << 5)));
      int chg = cb + c8 * 8;
      int h = (chg >> 6) & 7, d = chg & 63;
      int ng = m0 + nl, wL = ng >> 9, nn = ng & 511;
      _Float16* panel = qkv + ((size_t)(wL * 24 + j * 8 + h) << 15);
      *(half8_t*)(panel + (size_t)nn * 64 + d) = vv;
    }
  }
}

// ---------------- attention: swapped QK^T, lane-local softmax, zero LDS ----------------
__global__ __launch_bounds__(256) void attn_win(_Float16* __restrict__ qkv) {
  const int tid = threadIdx.x;
  const int l = tid & 63;
  const int wid = tid >> 6;
  const int q32 = l & 31;
  const int h2 = l >> 5;
  const int b = blockIdx.x;
  const int qc = b & 3;
  const int h = (b >> 2) & 7;
  const int w = b >> 5;
  _Float16* Qp = qkv + ((size_t)(w * 24 + h) << 15);
  const _Float16* Kp = qkv + ((size_t)(w * 24 + 8 + h) << 15);
  const _Float16* Vp = qkv + ((size_t)(w * 24 + 16 + h) << 15);
  const int qrow = qc * 128 + wid * 32 + q32;

  half8_t qf[4];
#pragma unroll
  for (int j = 0; j < 4; ++j)
    qf[j] = *(const half8_t*)(Qp + (size_t)qrow * 64 + j * 16 + h2 * 8);

  f32x16 o0 = {}, o1 = {};
  float m_run = -1e30f, lsum = 0.f;

  for (int kt = 0; kt < 16; ++kt) {
    half8_t kf[4];
#pragma unroll
    for (int j = 0; j < 4; ++j)
      kf[j] = *(const half8_t*)(Kp + (size_t)(kt * 32 + q32) * 64 + j * 16 + h2 * 8);
    f32x16 s = {};
#pragma unroll
    for (int j = 0; j < 4; ++j)
      s = __builtin_amdgcn_mfma_f32_32x32x16_f16(kf[j], qf[j], s, 0, 0, 0);

    float tmax = s[0];
#pragma unroll
    for (int r = 1; r < 16; ++r) tmax = fmaxf(tmax, s[r]);
    tmax = fmaxf(tmax, __shfl_xor(tmax, 32));
    if (!__all(tmax <= m_run + 8.f)) {  // T13 defer-max
      float mNew = fmaxf(m_run, tmax);
      float sc = __expf(m_run - mNew);
      lsum *= sc;
#pragma unroll
      for (int r = 0; r < 16; ++r) { o0[r] *= sc; o1[r] *= sc; }
      m_run = mNew;
    }
    float p[16], tsum = 0.f;
#pragma unroll
    for (int r = 0; r < 16; ++r) { p[r] = __expf(s[r] - m_run); tsum += p[r]; }
    tsum += __shfl_xor(tsum, 32);
    lsum += tsum;

    half8_t pf0, pf1;
#pragma unroll
    for (int e = 0; e < 8; ++e) { pf0[e] = (_Float16)p[e]; pf1[e] = (_Float16)(p[8 + e]); }

    const _Float16* vb = Vp + (size_t)(kt * 4 + h2) * 512 + q32 * 8;
    half8_t vf;
    vf = *(const half8_t*)(vb);
    o0 = __builtin_amdgcn_mfma_f32_32x32x16_f16(vf, pf0, o0, 0, 0, 0);
    vf = *(const half8_t*)(vb + 256);
    o1 = __builtin_amdgcn_mfma_f32_32x32x16_f16(vf, pf0, o1, 0, 0, 0);
    vf = *(const half8_t*)(vb + 1024);
    o0 = __builtin_amdgcn_mfma_f32_32x32x16_f16(vf, pf1, o0, 0, 0, 0);
    vf = *(const half8_t*)(vb + 1280);
    o1 = __builtin_amdgcn_mfma_f32_32x32x16_f16(vf, pf1, o1, 0, 0, 0);
  }
  const float inv = 1.0f / lsum;
#pragma unroll
  for (int rq = 0; rq < 4; ++rq) {
    half4_t v0, v1;
#pragma unroll
    for (int i = 0; i < 4; ++i) {
      v0[i] = (_Float16)(o0[rq * 4 + i] * inv);
      v1[i] = (_Float16)(o1[rq * 4 + i] * inv);
    }
    *(half4_t*)(Qp + (size_t)qrow * 64 + 8 * rq + 4 * h2) = v0;
    *(half4_t*)(Qp + (size_t)qrow * 64 + 32 + 8 * rq + 4 * h2) = v1;
  }
}

// ---------------- GEMM2: out = attn_out @ Wproj + b ----------------
__global__ __launch_bounds__(256) void gemm2_proj(
    const _Float16* __restrict__ qkv,
    const _Float16* __restrict__ wpT,  // [512][512]
    const float* __restrict__ bias,    // [512]
    float* __restrict__ out) {
  const int tid = threadIdx.x, l = tid & 63;
  const int wid = tid >> 6, wr = wid >> 1, wc = wid & 1;
  const int lr = l & 15, lk8 = (l >> 4) * 8;
  const int m0 = blockIdx.x * 128, n0 = blockIdx.y * 128;
  size_t aBase[4];
#pragma unroll
  for (int mt = 0; mt < 4; ++mt) {
    int row = m0 + wr * 64 + mt * 16 + lr;
    int wL = row >> 9, n = row & 511;
    aBase[mt] = ((size_t)(wL * 24) << 15) + (size_t)n * 64 + lk8;
  }
  size_t bBase[4];
#pragma unroll
  for (int nt = 0; nt < 4; ++nt)
    bBase[nt] = (size_t)(n0 + wc * 64 + nt * 16 + lr) * 512 + lk8;

  f32x4 acc[4][4] = {};
  for (int ks = 0; ks < 16; ++ks) {
    half8_t a[4], b[4];
    size_t aoff = (size_t)(ks >> 1) * 32768 + (size_t)(ks & 1) * 32;
#pragma unroll
    for (int mt = 0; mt < 4; ++mt) a[mt] = *(const half8_t*)(qkv + aBase[mt] + aoff);
#pragma unroll
    for (int nt = 0; nt < 4; ++nt) b[nt] = *(const half8_t*)(wpT + bBase[nt] + ks * 32);
#pragma unroll
    for (int mt = 0; mt < 4; ++mt)
#pragma unroll
      for (int nt = 0; nt < 4; ++nt)
        acc[mt][nt] = __builtin_amdgcn_mfma_f32_16x16x32_f16(a[mt], b[nt], acc[mt][nt], 0, 0, 0);
  }
#pragma unroll
  for (int nt = 0; nt < 4; ++nt) {
    int col = n0 + wc * 64 + nt * 16 + lr;
    float bv = bias[col];
#pragma unroll
    for (int mt = 0; mt < 4; ++mt) {
      int row = m0 + wr * 64 + mt * 16 + ((l >> 4) << 2);
#pragma unroll
      for (int r = 0; r < 4; ++r)
        out[(size_t)(row + r) * 512 + col] = acc[mt][nt][r] + bv;
    }
  }
}

extern "C" void kernel_launch(void* const* d_in, const int* in_sizes, int n_in,
                              void* d_out, int out_size, void* d_ws, size_t ws_size,
                              hipStream_t stream) {
  const float* x = (const float*)d_in[0];
  const float* wqkv = (const float*)d_in[1];
  const float* bqkv = (const float*)d_in[2];
  const float* wproj = (const float*)d_in[3];
  const float* bproj = (const float*)d_in[4];
  float* out = (float*)d_out;

  _Float16* wqkvT = (_Float16*)d_ws;
  _Float16* wprojT = wqkvT + (size_t)TC * CDIM;
  _Float16* chunkws = wprojT + (size_t)CDIM * CDIM;
  const size_t fixed = ((size_t)TC * CDIM + (size_t)CDIM * CDIM) * sizeof(_Float16);
  // per window: x16 (512*512 halfs) + 24 qkv panels (24*32768 halfs)
  const size_t perwin = ((size_t)NTOK * CDIM + (size_t)24 * 32768) * sizeof(_Float16);
  int nw = 64;
  while (nw > 1 && fixed + (size_t)nw * perwin > ws_size) nw >>= 1;

  prep_weights<<<dim3(256), 256, 0, stream>>>(wqkv, wproj, wqkvT, wprojT);
  for (int wbase = 0; wbase < NWIN; wbase += nw) {
    const float* xc = x + (size_t)wbase * NTOK * CDIM;
    float* oc = out + (size_t)wbase * NTOK * CDIM;
    _Float16* x16 = chunkws;
    _Float16* qkvws = chunkws + (size_t)nw * NTOK * CDIM;
    const int n8 = nw * NTOK * CDIM / 8;
    cvt_x<<<dim3((n8 + 255) / 256), 256, 0, stream>>>(xc, x16, n8);
    gemm1_qkv<<<dim3(nw * 4, 12), 256, 0, stream>>>(x16, wqkvT, bqkv, qkvws);
    attn_win<<<dim3(nw * 32), 256, 0, stream>>>(qkvws);
    gemm2_proj<<<dim3(nw * 4, 4), 256, 0, stream>>>(qkvws, wprojT, bproj, oc);
  }
}